// Round 1
// baseline (1573.902 us; speedup 1.0000x reference)
//
#include <hip/hip_runtime.h>
#include <math.h>

// ---------------- constants (dims fixed by the problem) ----------------
#define INTER 128
#define OUTD  64
#define SCAN_T 256
#define SCAN_E 1024   // elements per scan block (4/thread)

// ---------------- CSR build ----------------
__global__ void count_k(const int* __restrict__ dst, int* __restrict__ cnt, int E) {
    int e = blockIdx.x * 256 + threadIdx.x;
    if (e < E) atomicAdd(&cnt[dst[e]], 1);
}

__global__ void dinv_k(const int* __restrict__ cnt, float* __restrict__ dinv, int N) {
    int i = blockIdx.x * 256 + threadIdx.x;
    if (i < N) dinv[i] = rsqrtf((float)(cnt[i] + 1));   // +1 self loop; deg>=1 always
}

__global__ void scan_block(const int* __restrict__ in, int* __restrict__ out,
                           int* __restrict__ bsums, int n) {
    __shared__ int sh[SCAN_T];
    int base = blockIdx.x * SCAN_E;
    int t = threadIdx.x;
    int v[4];
    int s = 0;
#pragma unroll
    for (int i = 0; i < 4; i++) {
        int idx = base + t * 4 + i;
        v[i] = (idx < n) ? in[idx] : 0;
        s += v[i];
    }
    sh[t] = s;
    __syncthreads();
    for (int off = 1; off < SCAN_T; off <<= 1) {
        int x = (t >= off) ? sh[t - off] : 0;
        __syncthreads();
        sh[t] += x;
        __syncthreads();
    }
    int excl = (t == 0) ? 0 : sh[t - 1];
    if (bsums && t == SCAN_T - 1) bsums[blockIdx.x] = sh[t];
#pragma unroll
    for (int i = 0; i < 4; i++) {
        int idx = base + t * 4 + i;
        if (idx < n) out[idx] = excl;
        excl += v[i];
    }
}

__global__ void scan_add(int* __restrict__ out, const int* __restrict__ bsums, int n, int total) {
    int idx = blockIdx.x * SCAN_E + threadIdx.x * 4;
    int add = bsums[blockIdx.x];
#pragma unroll
    for (int i = 0; i < 4; i++) {
        int j = idx + i;
        if (j < n) out[j] += add;
    }
    if (blockIdx.x == 0 && threadIdx.x == 0) out[n] = total;  // row_start[N] = E
}

__global__ void scatter_k(const int* __restrict__ src, const int* __restrict__ dst,
                          const int* __restrict__ rs, int* __restrict__ cursor,
                          const float* __restrict__ dinv,
                          int* __restrict__ col, float* __restrict__ wgt, int E) {
    int e = blockIdx.x * 256 + threadIdx.x;
    if (e >= E) return;
    int s = src[e], d = dst[e];
    int pos = rs[d] + atomicAdd(&cursor[d], 1);
    col[pos] = s;
    wgt[pos] = dinv[s] * dinv[d];
}

// ---------------- aggregation ----------------
// input layer: aggregate raw x (N x 2)
__global__ void agg2(const float* __restrict__ x, const int* __restrict__ rs,
                     const int* __restrict__ col, const float* __restrict__ wgt,
                     const float* __restrict__ dinv, float* __restrict__ ax, int N) {
    int i = blockIdx.x * 256 + threadIdx.x;
    if (i >= N) return;
    float di = dinv[i];
    float sn = di * di;
    float2 xv = ((const float2*)x)[i];
    float a0 = sn * xv.x, a1 = sn * xv.y;
    int e0 = rs[i], e1 = rs[i + 1];
    for (int k = e0; k < e1; k++) {
        int s = col[k];
        float wk = wgt[k];
        float2 xs = ((const float2*)x)[s];
        a0 += wk * xs.x;
        a1 += wk * xs.y;
    }
    ((float2*)ax)[i] = make_float2(a0, a1);
}

template <int F, bool RELU>
__global__ __launch_bounds__(256) void aggF(const float* __restrict__ M, const int* __restrict__ rs,
                                            const int* __restrict__ col, const float* __restrict__ wgt,
                                            const float* __restrict__ dinv, const float* __restrict__ bias,
                                            float* __restrict__ out, int N) {
    constexpr int NPB = 256 / F;
    int node = blockIdx.x * NPB + threadIdx.x / F;
    int f = threadIdx.x % F;
    if (node >= N) return;
    float di = dinv[node];
    float acc = di * di * M[(size_t)node * F + f];
    int e0 = rs[node], e1 = rs[node + 1];
    for (int k = e0; k < e1; k++) {
        acc = fmaf(wgt[k], M[(size_t)col[k] * F + f], acc);
    }
    acc += bias[f];
    if (RELU) acc = fmaxf(acc, 0.f);
    out[(size_t)node * F + f] = acc;
}

// ---------------- GEMMs ----------------
// input transform: h = ax (N x 2) @ W_in (2 x 128) + b_in
__global__ void gemm_in(const float* __restrict__ ax, const float* __restrict__ Wi,
                        const float* __restrict__ bi, float* __restrict__ h, int N) {
    int node = blockIdx.x * 2 + threadIdx.x / 128;
    int j = threadIdx.x % 128;
    if (node >= N) return;
    float2 a = ((const float2*)ax)[node];
    h[(size_t)node * 128 + j] = fmaf(a.x, Wi[j], fmaf(a.y, Wi[128 + j], bi[j]));
}

// main GEMM: M = H (N x 128) @ W (128 x OUTC), K = 128
template <int OUTC>
__global__ __launch_bounds__(256) void gemm128(const float* __restrict__ H, const float* __restrict__ W,
                                               float* __restrict__ Mo, int N) {
    constexpr int K = 128;
    constexpr int KC = 32;                 // K chunk
    constexpr int BN = 64;                 // nodes per block
    constexpr int TX = OUTC / 4;           // 32 or 16
    constexpr int TY = 256 / TX;           // 8 or 16
    constexpr int NPT = BN / TY;           // 8 or 4
    constexpr int BNP = BN + 4;            // padded (68) -> 272B rows, 16B aligned
    __shared__ __align__(16) float Wlds[KC * OUTC];
    __shared__ __align__(16) float Ht[KC * BNP];
    const int tid = threadIdx.x;
    const int tx = tid % TX;
    const int ty = tid / TX;
    const int node0 = blockIdx.x * BN;
    float acc[NPT][4];
#pragma unroll
    for (int n = 0; n < NPT; n++) acc[n][0] = acc[n][1] = acc[n][2] = acc[n][3] = 0.f;

    for (int k0 = 0; k0 < K; k0 += KC) {
        // stage W chunk (contiguous KC*OUTC floats)
        constexpr int WV = KC * OUTC / (4 * 256);
#pragma unroll
        for (int v = 0; v < WV; v++) {
            int idx = (tid + v * 256) * 4;
            *(float4*)&Wlds[idx] = *(const float4*)&W[(size_t)k0 * OUTC + idx];
        }
        // stage H chunk transposed: Ht[kk][node]
#pragma unroll
        for (int v = 0; v < 2; v++) {
            int t = tid + v * 256;
            int row = t / 8;   // 0..63
            int c4 = t % 8;    // 0..7
            int gnode = node0 + row;
            float4 hv;
            if (gnode < N)
                hv = *(const float4*)&H[(size_t)gnode * K + k0 + c4 * 4];
            else
                hv = make_float4(0.f, 0.f, 0.f, 0.f);
            Ht[(c4 * 4 + 0) * BNP + row] = hv.x;
            Ht[(c4 * 4 + 1) * BNP + row] = hv.y;
            Ht[(c4 * 4 + 2) * BNP + row] = hv.z;
            Ht[(c4 * 4 + 3) * BNP + row] = hv.w;
        }
        __syncthreads();
#pragma unroll
        for (int kk = 0; kk < KC; kk++) {
            float4 wv = *(const float4*)&Wlds[kk * OUTC + tx * 4];
#pragma unroll
            for (int n4 = 0; n4 < NPT / 4; n4++) {
                float4 hv = *(const float4*)&Ht[kk * BNP + ty * NPT + n4 * 4];
                float hvals[4] = {hv.x, hv.y, hv.z, hv.w};
#pragma unroll
                for (int i = 0; i < 4; i++) {
                    acc[n4 * 4 + i][0] = fmaf(hvals[i], wv.x, acc[n4 * 4 + i][0]);
                    acc[n4 * 4 + i][1] = fmaf(hvals[i], wv.y, acc[n4 * 4 + i][1]);
                    acc[n4 * 4 + i][2] = fmaf(hvals[i], wv.z, acc[n4 * 4 + i][2]);
                    acc[n4 * 4 + i][3] = fmaf(hvals[i], wv.w, acc[n4 * 4 + i][3]);
                }
            }
        }
        __syncthreads();
    }
#pragma unroll
    for (int n = 0; n < NPT; n++) {
        int gnode = node0 + ty * NPT + n;
        if (gnode < N) {
            *(float4*)&Mo[(size_t)gnode * OUTC + tx * 4] =
                make_float4(acc[n][0], acc[n][1], acc[n][2], acc[n][3]);
        }
    }
}

// ---------------- pooling ----------------
__global__ __launch_bounds__(256) void pool_k(const float* __restrict__ nod, const int* __restrict__ batch,
                                              float* __restrict__ pool, int N) {
    int wave = threadIdx.x / 64;
    int f = threadIdx.x % 64;
    int start = blockIdx.x * 2048 + wave * 512;
    if (start >= N) return;
    int end = min(start + 512, N);
    int cur = batch[start];
    float acc = 0.f;
    for (int i = start; i < end; i++) {
        int g = batch[i];
        if (g != cur) {
            atomicAdd(&pool[cur * 64 + f], acc);
            acc = 0.f;
            cur = g;
        }
        acc += nod[(size_t)i * 64 + f];
    }
    atomicAdd(&pool[cur * 64 + f], acc);
}

__global__ void final_k(const float* __restrict__ pool, const int* __restrict__ batch,
                        float* __restrict__ out, int N) {
    int tid = threadIdx.x;   // 512 = 8 graphs * 64 feats
    int g = tid / 64;
    int f = tid % 64;
    // lower_bound boundaries in sorted batch
    int lo = 0, hi = N;
    while (lo < hi) { int mid = (lo + hi) >> 1; if (batch[mid] < g) lo = mid + 1; else hi = mid; }
    int b0 = lo;
    lo = 0; hi = N;
    while (lo < hi) { int mid = (lo + hi) >> 1; if (batch[mid] < g + 1) lo = mid + 1; else hi = mid; }
    int c = lo - b0;
    float v = pool[g * 64 + f] / (float)max(c, 1);
    out[g * 64 + f] = 1.f / (1.f + expf(-v));
}

// ---------------- launch ----------------
extern "C" void kernel_launch(void* const* d_in, const int* in_sizes, int n_in,
                              void* d_out, int out_size, void* d_ws, size_t ws_size,
                              hipStream_t stream) {
    const float* x     = (const float*)d_in[0];
    const int*   ei    = (const int*)d_in[1];
    const int*   batch = (const int*)d_in[2];
    const float* W_in  = (const float*)d_in[3];
    const float* b_in  = (const float*)d_in[4];
    const float* W_h   = (const float*)d_in[5];
    const float* b_h   = (const float*)d_in[6];
    const float* W_out = (const float*)d_in[7];
    const float* b_out = (const float*)d_in[8];

    const int N = in_sizes[2];
    const int E = in_sizes[1] / 2;
    const int L = in_sizes[5] / (INTER * INTER);
    const int* src = ei;
    const int* dst = ei + E;

    // workspace bump allocator
    char* ws = (char*)d_ws;
    size_t off = 0;
    auto alloc = [&](size_t bytes) -> void* {
        void* p = ws + off;
        off += (bytes + 255) & ~(size_t)255;
        return p;
    };
    int*   cnt    = (int*)alloc((size_t)N * 4);
    int*   cursor = (int*)alloc((size_t)N * 4);
    int*   rs     = (int*)alloc((size_t)(N + 1) * 4);
    int*   bsums  = (int*)alloc(4096);
    float* dinv   = (float*)alloc((size_t)N * 4);
    int*   col    = (int*)alloc((size_t)E * 4);
    float* wgt    = (float*)alloc((size_t)E * 4);
    float* ax     = (float*)alloc((size_t)N * 2 * 4);
    float* h      = (float*)alloc((size_t)N * INTER * 4);
    float* m      = (float*)alloc((size_t)N * INTER * 4);
    float* pool   = (float*)alloc(512 * 4);
    (void)ws_size; (void)n_in;

    hipMemsetAsync(cnt, 0, (size_t)N * 4, stream);
    hipMemsetAsync(cursor, 0, (size_t)N * 4, stream);
    hipMemsetAsync(pool, 0, 512 * 4, stream);

    // CSR build
    count_k<<<(E + 255) / 256, 256, 0, stream>>>(dst, cnt, E);
    dinv_k<<<(N + 255) / 256, 256, 0, stream>>>(cnt, dinv, N);
    int nsb = (N + SCAN_E - 1) / SCAN_E;
    scan_block<<<nsb, SCAN_T, 0, stream>>>(cnt, rs, bsums, N);
    scan_block<<<1, SCAN_T, 0, stream>>>(bsums, bsums, nullptr, nsb);
    scan_add<<<nsb, SCAN_T, 0, stream>>>(rs, bsums, N, E);
    scatter_k<<<(E + 255) / 256, 256, 0, stream>>>(src, dst, rs, cursor, dinv, col, wgt, E);

    // input layer: aggregate x then transform
    agg2<<<(N + 255) / 256, 256, 0, stream>>>(x, rs, col, wgt, dinv, ax, N);
    gemm_in<<<(N + 1) / 2, 256, 0, stream>>>(ax, W_in, b_in, h, N);

    // hidden layers: transform then aggregate (+bias, relu)
    for (int l = 0; l < L; l++) {
        gemm128<INTER><<<(N + 63) / 64, 256, 0, stream>>>(h, W_h + (size_t)l * INTER * INTER, m, N);
        aggF<INTER, true><<<(N + 1) / 2, 256, 0, stream>>>(m, rs, col, wgt, dinv, b_h + (size_t)l * INTER, h, N);
    }

    // output layer: transform to 64 then aggregate (+bias)
    gemm128<OUTD><<<(N + 63) / 64, 256, 0, stream>>>(h, W_out, m, N);
    aggF<OUTD, false><<<(N + 3) / 4, 256, 0, stream>>>(m, rs, col, wgt, dinv, b_out, h, N);

    // mean pool + sigmoid
    pool_k<<<(N + 2047) / 2048, 256, 0, stream>>>(h, batch, pool, N);
    final_k<<<1, 512, 0, stream>>>(pool, batch, (float*)d_out, N);
}

// Round 2
// 807.703 us; speedup vs baseline: 1.9486x; 1.9486x over previous
//
#include <hip/hip_runtime.h>
#include <math.h>

// ---------------- constants ----------------
#define INTER 128
#define OUTD  64
#define SCAN_T 256
#define SCAN_E 1024

using bf16x8 = __attribute__((ext_vector_type(8))) short;
using f32x4  = __attribute__((ext_vector_type(4))) float;

static __device__ __forceinline__ unsigned short f2bf(float f) {
    unsigned int u = __float_as_uint(f);
    u += 0x7fffu + ((u >> 16) & 1u);          // RTNE
    return (unsigned short)(u >> 16);
}
static __device__ __forceinline__ float bflo(unsigned int u) { return __uint_as_float(u << 16); }
static __device__ __forceinline__ float bfhi(unsigned int u) { return __uint_as_float(u & 0xffff0000u); }

// ---------------- CSR build ----------------
__global__ void count_k(const int* __restrict__ dst, int* __restrict__ cnt, int E) {
    int e = blockIdx.x * 256 + threadIdx.x;
    if (e < E) atomicAdd(&cnt[dst[e]], 1);
}

__global__ void dinv_k(const int* __restrict__ cnt, float* __restrict__ dinv, int N) {
    int i = blockIdx.x * 256 + threadIdx.x;
    if (i < N) dinv[i] = rsqrtf((float)(cnt[i] + 1));
}

__global__ void scan_block(const int* __restrict__ in, int* __restrict__ out,
                           int* __restrict__ bsums, int n) {
    __shared__ int sh[SCAN_T];
    int base = blockIdx.x * SCAN_E;
    int t = threadIdx.x;
    int v[4];
    int s = 0;
#pragma unroll
    for (int i = 0; i < 4; i++) {
        int idx = base + t * 4 + i;
        v[i] = (idx < n) ? in[idx] : 0;
        s += v[i];
    }
    sh[t] = s;
    __syncthreads();
    for (int off = 1; off < SCAN_T; off <<= 1) {
        int x = (t >= off) ? sh[t - off] : 0;
        __syncthreads();
        sh[t] += x;
        __syncthreads();
    }
    int excl = (t == 0) ? 0 : sh[t - 1];
    if (bsums && t == SCAN_T - 1) bsums[blockIdx.x] = sh[t];
#pragma unroll
    for (int i = 0; i < 4; i++) {
        int idx = base + t * 4 + i;
        if (idx < n) out[idx] = excl;
        excl += v[i];
    }
}

__global__ void scan_add(int* __restrict__ out, const int* __restrict__ bsums, int n, int total) {
    int idx = blockIdx.x * SCAN_E + threadIdx.x * 4;
    int add = bsums[blockIdx.x];
#pragma unroll
    for (int i = 0; i < 4; i++) {
        int j = idx + i;
        if (j < n) out[j] += add;
    }
    if (blockIdx.x == 0 && threadIdx.x == 0) out[n] = total;
}

__global__ void scatter_k(const int* __restrict__ src, const int* __restrict__ dst,
                          const int* __restrict__ rs, int* __restrict__ cursor,
                          const float* __restrict__ dinv,
                          int2* __restrict__ cw, int E) {
    int e = blockIdx.x * 256 + threadIdx.x;
    if (e >= E) return;
    int s = src[e], d = dst[e];
    int pos = rs[d] + atomicAdd(&cursor[d], 1);
    cw[pos] = make_int2(s, __float_as_int(dinv[s] * dinv[d]));
}

// ---------------- weight prep (fp32 -> bf16, transposed [n][k]) ----------------
__global__ void wprep_h(const float* __restrict__ W, unsigned short* __restrict__ Wt, int L) {
    int tid = blockIdx.x * 256 + threadIdx.x;
    if (tid >= L * INTER * INTER) return;
    int l = tid / (INTER * INTER);
    int r = tid % (INTER * INTER);
    int n = r / INTER, k = r % INTER;
    Wt[tid] = f2bf(W[(size_t)l * INTER * INTER + (size_t)k * INTER + n]);
}

__global__ void wprep_o(const float* __restrict__ W, unsigned short* __restrict__ Wt) {
    int tid = blockIdx.x * 256 + threadIdx.x;
    if (tid >= OUTD * INTER) return;
    int n = tid / INTER, k = tid % INTER;
    Wt[tid] = f2bf(W[(size_t)k * OUTD + n]);
}

// ---------------- input layer ----------------
__global__ void agg2(const float* __restrict__ x, const int* __restrict__ rs,
                     const int2* __restrict__ cw, const float* __restrict__ dinv,
                     float* __restrict__ ax, int N) {
    int i = blockIdx.x * 256 + threadIdx.x;
    if (i >= N) return;
    float di = dinv[i];
    float sn = di * di;
    float2 xv = ((const float2*)x)[i];
    float a0 = sn * xv.x, a1 = sn * xv.y;
    int e0 = rs[i], e1 = rs[i + 1];
    for (int k = e0; k < e1; k++) {
        int2 c = cw[k];
        float wk = __int_as_float(c.y);
        float2 xs = ((const float2*)x)[c.x];
        a0 += wk * xs.x;
        a1 += wk * xs.y;
    }
    ((float2*)ax)[i] = make_float2(a0, a1);
}

// h = ax (N x 2) @ W_in (2 x 128) + b_in  -> bf16
__global__ void gemm_in(const float* __restrict__ ax, const float* __restrict__ Wi,
                        const float* __restrict__ bi, unsigned short* __restrict__ h, int N) {
    int node = blockIdx.x * 2 + threadIdx.x / 128;
    int j = threadIdx.x % 128;
    if (node >= N) return;
    float2 a = ((const float2*)ax)[node];
    h[(size_t)node * 128 + j] = f2bf(fmaf(a.x, Wi[j], fmaf(a.y, Wi[128 + j], bi[j])));
}

// ---------------- MFMA GEMM: M = H (N x 128) @ W (128 x OUTC), bf16 ----------------
// A-frag: lane holds A[lane&15][(lane>>4)*8 + j (+32*ks)]
// B-frag: lane holds B[(lane>>4)*8 + j (+32*ks)][lane&15]  (from Wt[n][k])
// D:      lane holds D[(lane>>4)*4 + j][lane&15]
template <int OUTC>
__global__ __launch_bounds__(256) void gemm_mfma(const unsigned short* __restrict__ H,
                                                 const unsigned short* __restrict__ Wt,
                                                 unsigned short* __restrict__ M, int N) {
    const int wave = threadIdx.x >> 6;
    const int lane = threadIdx.x & 63;
    const int r15 = lane & 15;
    const int kg = lane >> 4;
    const int node0 = blockIdx.x * 64 + wave * 16;
    if (node0 >= N) return;

    int arow = node0 + r15;
    if (arow >= N) arow = N - 1;
    const unsigned short* hrow = H + (size_t)arow * 128 + kg * 8;
    bf16x8 a[4];
#pragma unroll
    for (int ks = 0; ks < 4; ks++) a[ks] = *(const bf16x8*)(hrow + ks * 32);

    constexpr int NC = OUTC / 16;
    f32x4 acc[NC];
#pragma unroll
    for (int c = 0; c < NC; c++) acc[c] = (f32x4){0.f, 0.f, 0.f, 0.f};

#pragma unroll
    for (int c = 0; c < NC; c++) {
        const unsigned short* wrow = Wt + (size_t)(c * 16 + r15) * 128 + kg * 8;
#pragma unroll
        for (int ks = 0; ks < 4; ks++) {
            bf16x8 b = *(const bf16x8*)(wrow + ks * 32);
            acc[c] = __builtin_amdgcn_mfma_f32_16x16x32_bf16(a[ks], b, acc[c], 0, 0, 0);
        }
    }

#pragma unroll
    for (int j = 0; j < 4; j++) {
        int node = node0 + kg * 4 + j;
        if (node < N) {
#pragma unroll
            for (int c = 0; c < NC; c++)
                M[(size_t)node * OUTC + c * 16 + r15] = f2bf(acc[c][j]);
        }
    }
}

// ---------------- aggregation over bf16 rows ----------------
// F feats, LPN = F/8 lanes per node, each lane owns 8 contiguous feats (16B).
template <int F, bool RELU, bool F32OUT>
__global__ __launch_bounds__(256) void aggB(const unsigned short* __restrict__ M,
                                            const int* __restrict__ rs,
                                            const int2* __restrict__ cw,
                                            const float* __restrict__ dinv,
                                            const float* __restrict__ bias,
                                            void* __restrict__ outp, int N) {
    constexpr int LPN = F / 8;
    constexpr int NPB = 256 / LPN;
    int g = threadIdx.x / LPN;
    int q = threadIdx.x % LPN;
    int node = blockIdx.x * NPB + g;
    if (node >= N) return;

    float di = dinv[node];
    float sn = di * di;
    float acc[8];
    {
        uint4 v = *(const uint4*)(M + (size_t)node * F + q * 8);
        acc[0] = sn * bflo(v.x); acc[1] = sn * bfhi(v.x);
        acc[2] = sn * bflo(v.y); acc[3] = sn * bfhi(v.y);
        acc[4] = sn * bflo(v.z); acc[5] = sn * bfhi(v.z);
        acc[6] = sn * bflo(v.w); acc[7] = sn * bfhi(v.w);
    }
    int e0 = rs[node], e1 = rs[node + 1];
    int k = e0;
    for (; k + 1 < e1; k += 2) {
        int2 c0 = cw[k];
        int2 c1 = cw[k + 1];
        uint4 v0 = *(const uint4*)(M + (size_t)c0.x * F + q * 8);
        uint4 v1 = *(const uint4*)(M + (size_t)c1.x * F + q * 8);
        float w0 = __int_as_float(c0.y);
        float w1 = __int_as_float(c1.y);
        acc[0] = fmaf(w0, bflo(v0.x), acc[0]); acc[1] = fmaf(w0, bfhi(v0.x), acc[1]);
        acc[2] = fmaf(w0, bflo(v0.y), acc[2]); acc[3] = fmaf(w0, bfhi(v0.y), acc[3]);
        acc[4] = fmaf(w0, bflo(v0.z), acc[4]); acc[5] = fmaf(w0, bfhi(v0.z), acc[5]);
        acc[6] = fmaf(w0, bflo(v0.w), acc[6]); acc[7] = fmaf(w0, bfhi(v0.w), acc[7]);
        acc[0] = fmaf(w1, bflo(v1.x), acc[0]); acc[1] = fmaf(w1, bfhi(v1.x), acc[1]);
        acc[2] = fmaf(w1, bflo(v1.y), acc[2]); acc[3] = fmaf(w1, bfhi(v1.y), acc[3]);
        acc[4] = fmaf(w1, bflo(v1.z), acc[4]); acc[5] = fmaf(w1, bfhi(v1.z), acc[5]);
        acc[6] = fmaf(w1, bflo(v1.w), acc[6]); acc[7] = fmaf(w1, bfhi(v1.w), acc[7]);
    }
    if (k < e1) {
        int2 c0 = cw[k];
        uint4 v0 = *(const uint4*)(M + (size_t)c0.x * F + q * 8);
        float w0 = __int_as_float(c0.y);
        acc[0] = fmaf(w0, bflo(v0.x), acc[0]); acc[1] = fmaf(w0, bfhi(v0.x), acc[1]);
        acc[2] = fmaf(w0, bflo(v0.y), acc[2]); acc[3] = fmaf(w0, bfhi(v0.y), acc[3]);
        acc[4] = fmaf(w0, bflo(v0.z), acc[4]); acc[5] = fmaf(w0, bfhi(v0.z), acc[5]);
        acc[6] = fmaf(w0, bflo(v0.w), acc[6]); acc[7] = fmaf(w0, bfhi(v0.w), acc[7]);
    }
#pragma unroll
    for (int j = 0; j < 8; j++) {
        acc[j] += bias[q * 8 + j];
        if (RELU) acc[j] = fmaxf(acc[j], 0.f);
    }
    if (F32OUT) {
        float* out = (float*)outp;
        *(float4*)(out + (size_t)node * F + q * 8) = make_float4(acc[0], acc[1], acc[2], acc[3]);
        *(float4*)(out + (size_t)node * F + q * 8 + 4) = make_float4(acc[4], acc[5], acc[6], acc[7]);
    } else {
        unsigned short* out = (unsigned short*)outp;
        uint4 o;
        o.x = (unsigned int)f2bf(acc[0]) | ((unsigned int)f2bf(acc[1]) << 16);
        o.y = (unsigned int)f2bf(acc[2]) | ((unsigned int)f2bf(acc[3]) << 16);
        o.z = (unsigned int)f2bf(acc[4]) | ((unsigned int)f2bf(acc[5]) << 16);
        o.w = (unsigned int)f2bf(acc[6]) | ((unsigned int)f2bf(acc[7]) << 16);
        *(uint4*)(out + (size_t)node * F + q * 8) = o;
    }
}

// ---------------- pooling ----------------
__global__ __launch_bounds__(256) void pool_k(const float* __restrict__ nod, const int* __restrict__ batch,
                                              float* __restrict__ pool, int N) {
    int wave = threadIdx.x / 64;
    int f = threadIdx.x % 64;
    int start = blockIdx.x * 2048 + wave * 512;
    if (start >= N) return;
    int end = min(start + 512, N);
    int cur = batch[start];
    float acc = 0.f;
    for (int i = start; i < end; i++) {
        int g = batch[i];
        if (g != cur) {
            atomicAdd(&pool[cur * 64 + f], acc);
            acc = 0.f;
            cur = g;
        }
        acc += nod[(size_t)i * 64 + f];
    }
    atomicAdd(&pool[cur * 64 + f], acc);
}

__global__ void final_k(const float* __restrict__ pool, const int* __restrict__ batch,
                        float* __restrict__ out, int N) {
    int tid = threadIdx.x;
    int g = tid / 64;
    int f = tid % 64;
    int lo = 0, hi = N;
    while (lo < hi) { int mid = (lo + hi) >> 1; if (batch[mid] < g) lo = mid + 1; else hi = mid; }
    int b0 = lo;
    lo = 0; hi = N;
    while (lo < hi) { int mid = (lo + hi) >> 1; if (batch[mid] < g + 1) lo = mid + 1; else hi = mid; }
    int c = lo - b0;
    float v = pool[g * 64 + f] / (float)max(c, 1);
    out[g * 64 + f] = 1.f / (1.f + expf(-v));
}

// ---------------- launch ----------------
extern "C" void kernel_launch(void* const* d_in, const int* in_sizes, int n_in,
                              void* d_out, int out_size, void* d_ws, size_t ws_size,
                              hipStream_t stream) {
    const float* x     = (const float*)d_in[0];
    const int*   ei    = (const int*)d_in[1];
    const int*   batch = (const int*)d_in[2];
    const float* W_in  = (const float*)d_in[3];
    const float* b_in  = (const float*)d_in[4];
    const float* W_h   = (const float*)d_in[5];
    const float* b_h   = (const float*)d_in[6];
    const float* W_out = (const float*)d_in[7];
    const float* b_out = (const float*)d_in[8];

    const int N = in_sizes[2];
    const int E = in_sizes[1] / 2;
    const int L = in_sizes[5] / (INTER * INTER);
    const int* src = ei;
    const int* dst = ei + E;

    char* ws = (char*)d_ws;
    size_t off = 0;
    auto alloc = [&](size_t bytes) -> void* {
        void* p = ws + off;
        off += (bytes + 255) & ~(size_t)255;
        return p;
    };
    int*   cnt    = (int*)alloc((size_t)N * 4);
    int*   cursor = (int*)alloc((size_t)N * 4);
    int*   rs     = (int*)alloc((size_t)(N + 1) * 4);
    int*   bsums  = (int*)alloc(4096);
    float* dinv   = (float*)alloc((size_t)N * 4);
    int2*  cw     = (int2*)alloc((size_t)E * 8);
    float* ax     = (float*)alloc((size_t)N * 2 * 4);
    unsigned short* h   = (unsigned short*)alloc((size_t)N * INTER * 2);
    unsigned short* m   = (unsigned short*)alloc((size_t)N * INTER * 2);
    float* hout  = (float*)alloc((size_t)N * OUTD * 4);
    unsigned short* Wht = (unsigned short*)alloc((size_t)L * INTER * INTER * 2);
    unsigned short* Wot = (unsigned short*)alloc((size_t)OUTD * INTER * 2);
    float* pool   = (float*)alloc(512 * 4);
    (void)ws_size; (void)n_in;

    hipMemsetAsync(cnt, 0, (size_t)N * 4, stream);
    hipMemsetAsync(cursor, 0, (size_t)N * 4, stream);
    hipMemsetAsync(pool, 0, 512 * 4, stream);

    // CSR build
    count_k<<<(E + 255) / 256, 256, 0, stream>>>(dst, cnt, E);
    dinv_k<<<(N + 255) / 256, 256, 0, stream>>>(cnt, dinv, N);
    int nsb = (N + SCAN_E - 1) / SCAN_E;
    scan_block<<<nsb, SCAN_T, 0, stream>>>(cnt, rs, bsums, N);
    scan_block<<<1, SCAN_T, 0, stream>>>(bsums, bsums, nullptr, nsb);
    scan_add<<<nsb, SCAN_T, 0, stream>>>(rs, bsums, N, E);
    scatter_k<<<(E + 255) / 256, 256, 0, stream>>>(src, dst, rs, cursor, dinv, cw, E);

    // weight prep
    wprep_h<<<(L * INTER * INTER + 255) / 256, 256, 0, stream>>>(W_h, Wht, L);
    wprep_o<<<(OUTD * INTER + 255) / 256, 256, 0, stream>>>(W_out, Wot);

    // input layer
    agg2<<<(N + 255) / 256, 256, 0, stream>>>(x, rs, cw, dinv, ax, N);
    gemm_in<<<(N + 1) / 2, 256, 0, stream>>>(ax, W_in, b_in, h, N);

    // hidden layers
    for (int l = 0; l < L; l++) {
        gemm_mfma<INTER><<<(N + 63) / 64, 256, 0, stream>>>(h, Wht + (size_t)l * INTER * INTER, m, N);
        aggB<INTER, true, false><<<(N + 15) / 16, 256, 0, stream>>>(m, rs, cw, dinv, b_h + (size_t)l * INTER, h, N);
    }

    // output layer
    gemm_mfma<OUTD><<<(N + 63) / 64, 256, 0, stream>>>(h, Wot, m, N);
    aggB<OUTD, false, true><<<(N + 31) / 32, 256, 0, stream>>>(m, rs, cw, dinv, b_out, hout, N);

    // mean pool + sigmoid
    pool_k<<<(N + 2047) / 2048, 256, 0, stream>>>(hout, batch, pool, N);
    final_k<<<1, 512, 0, stream>>>(pool, batch, (float*)d_out, N);
}

// Round 5
// 674.841 us; speedup vs baseline: 2.3323x; 1.1969x over previous
//
#include <hip/hip_runtime.h>
#include <math.h>

// ---------------- constants ----------------
#define INTER 128
#define OUTD  64
#define SCAN_T 256
#define SCAN_E 1024
#define SPG   64    // pool blocks per graph

using bf16x8 = __attribute__((ext_vector_type(8))) short;
using f32x4  = __attribute__((ext_vector_type(4))) float;

static __device__ __forceinline__ unsigned short f2bf(float f) {
    unsigned int u = __float_as_uint(f);
    u += 0x7fffu + ((u >> 16) & 1u);          // RTNE
    return (unsigned short)(u >> 16);
}
static __device__ __forceinline__ float bflo(unsigned int u) { return __uint_as_float(u << 16); }
static __device__ __forceinline__ float bfhi(unsigned int u) { return __uint_as_float(u & 0xffff0000u); }

static __device__ __forceinline__ void fma8(float* a, float w, uint4 v) {
    a[0] = fmaf(w, bflo(v.x), a[0]); a[1] = fmaf(w, bfhi(v.x), a[1]);
    a[2] = fmaf(w, bflo(v.y), a[2]); a[3] = fmaf(w, bfhi(v.y), a[3]);
    a[4] = fmaf(w, bflo(v.z), a[4]); a[5] = fmaf(w, bfhi(v.z), a[5]);
    a[6] = fmaf(w, bflo(v.w), a[6]); a[7] = fmaf(w, bfhi(v.w), a[7]);
}

// ---------------- CSR build ----------------
__global__ void count_k(const int* __restrict__ dst, int* __restrict__ cnt, int E) {
    int e = blockIdx.x * 256 + threadIdx.x;
    if (e < E) atomicAdd(&cnt[dst[e]], 1);
}

__global__ void dinv_k(const int* __restrict__ cnt, float* __restrict__ dinv, int N) {
    int i = blockIdx.x * 256 + threadIdx.x;
    if (i < N) dinv[i] = rsqrtf((float)(cnt[i] + 1));
}

__global__ void scan_block(const int* __restrict__ in, int* __restrict__ out,
                           int* __restrict__ bsums, int n) {
    __shared__ int sh[SCAN_T];
    int base = blockIdx.x * SCAN_E;
    int t = threadIdx.x;
    int v[4];
    int s = 0;
#pragma unroll
    for (int i = 0; i < 4; i++) {
        int idx = base + t * 4 + i;
        v[i] = (idx < n) ? in[idx] : 0;
        s += v[i];
    }
    sh[t] = s;
    __syncthreads();
    for (int off = 1; off < SCAN_T; off <<= 1) {
        int x = (t >= off) ? sh[t - off] : 0;
        __syncthreads();
        sh[t] += x;
        __syncthreads();
    }
    int excl = (t == 0) ? 0 : sh[t - 1];
    if (bsums && t == SCAN_T - 1) bsums[blockIdx.x] = sh[t];
#pragma unroll
    for (int i = 0; i < 4; i++) {
        int idx = base + t * 4 + i;
        if (idx < n) out[idx] = excl;
        excl += v[i];
    }
}

__global__ void scan_add(int* __restrict__ out, const int* __restrict__ bsums, int n, int total) {
    int idx = blockIdx.x * SCAN_E + threadIdx.x * 4;
    int add = bsums[blockIdx.x];
#pragma unroll
    for (int i = 0; i < 4; i++) {
        int j = idx + i;
        if (j < n) out[j] += add;
    }
    if (blockIdx.x == 0 && threadIdx.x == 0) out[n] = total;
}

__global__ void scatter_k(const int* __restrict__ src, const int* __restrict__ dst,
                          const int* __restrict__ rs, int* __restrict__ cursor,
                          const float* __restrict__ dinv,
                          int2* __restrict__ cw, int E) {
    int e = blockIdx.x * 256 + threadIdx.x;
    if (e >= E) return;
    int s = src[e], d = dst[e];
    int pos = rs[d] + atomicAdd(&cursor[d], 1);
    cw[pos] = make_int2(s, __float_as_int(dinv[s] * dinv[d]));
}

// ---------------- weight prep (fp32 -> bf16, transposed [n][k]) ----------------
__global__ void wprep_h(const float* __restrict__ W, unsigned short* __restrict__ Wt, int L) {
    int tid = blockIdx.x * 256 + threadIdx.x;
    if (tid >= L * INTER * INTER) return;
    int l = tid / (INTER * INTER);
    int r = tid % (INTER * INTER);
    int n = r / INTER, k = r % INTER;
    Wt[tid] = f2bf(W[(size_t)l * INTER * INTER + (size_t)k * INTER + n]);
}

__global__ void wprep_o(const float* __restrict__ W, unsigned short* __restrict__ Wt) {
    int tid = blockIdx.x * 256 + threadIdx.x;
    if (tid >= OUTD * INTER) return;
    int n = tid / INTER, k = tid % INTER;
    Wt[tid] = f2bf(W[(size_t)k * OUTD + n]);
}

// ---------------- input layer ----------------
__global__ void agg2(const float* __restrict__ x, const int* __restrict__ rs,
                     const int2* __restrict__ cw, const float* __restrict__ dinv,
                     float* __restrict__ ax, int N) {
    int i = blockIdx.x * 256 + threadIdx.x;
    if (i >= N) return;
    float di = dinv[i];
    float sn = di * di;
    float2 xv = ((const float2*)x)[i];
    float a0 = sn * xv.x, a1 = sn * xv.y;
    int e0 = rs[i], e1 = rs[i + 1];
    for (int k = e0; k < e1; k++) {
        int2 c = cw[k];
        float wk = __int_as_float(c.y);
        float2 xs = ((const float2*)x)[c.x];
        a0 += wk * xs.x;
        a1 += wk * xs.y;
    }
    ((float2*)ax)[i] = make_float2(a0, a1);
}

// h = ax (N x 2) @ W_in (2 x 128) + b_in  -> bf16
__global__ void gemm_in(const float* __restrict__ ax, const float* __restrict__ Wi,
                        const float* __restrict__ bi, unsigned short* __restrict__ h, int N) {
    int node = blockIdx.x * 2 + threadIdx.x / 128;
    int j = threadIdx.x % 128;
    if (node >= N) return;
    float2 a = ((const float2*)ax)[node];
    h[(size_t)node * 128 + j] = f2bf(fmaf(a.x, Wi[j], fmaf(a.y, Wi[128 + j], bi[j])));
}

// ---------------- MFMA GEMM: M = H (N x 128) @ W (128 x OUTC), bf16 ----------------
template <int OUTC>
__global__ __launch_bounds__(256) void gemm_mfma(const unsigned short* __restrict__ H,
                                                 const unsigned short* __restrict__ Wt,
                                                 unsigned short* __restrict__ M, int N) {
    const int wave = threadIdx.x >> 6;
    const int lane = threadIdx.x & 63;
    const int r15 = lane & 15;
    const int kg = lane >> 4;
    const int node0 = blockIdx.x * 64 + wave * 16;
    if (node0 >= N) return;

    int arow = node0 + r15;
    if (arow >= N) arow = N - 1;
    const unsigned short* hrow = H + (size_t)arow * 128 + kg * 8;
    bf16x8 a[4];
#pragma unroll
    for (int ks = 0; ks < 4; ks++) a[ks] = *(const bf16x8*)(hrow + ks * 32);

    constexpr int NC = OUTC / 16;
    f32x4 acc[NC];
#pragma unroll
    for (int c = 0; c < NC; c++) acc[c] = (f32x4){0.f, 0.f, 0.f, 0.f};

#pragma unroll
    for (int c = 0; c < NC; c++) {
        const unsigned short* wrow = Wt + (size_t)(c * 16 + r15) * 128 + kg * 8;
#pragma unroll
        for (int ks = 0; ks < 4; ks++) {
            bf16x8 b = *(const bf16x8*)(wrow + ks * 32);
            acc[c] = __builtin_amdgcn_mfma_f32_16x16x32_bf16(a[ks], b, acc[c], 0, 0, 0);
        }
    }

#pragma unroll
    for (int j = 0; j < 4; j++) {
        int node = node0 + kg * 4 + j;
        if (node < N) {
#pragma unroll
            for (int c = 0; c < NC; c++)
                M[(size_t)node * OUTC + c * 16 + r15] = f2bf(acc[c][j]);
        }
    }
}

// ---------------- aggregation over bf16 rows (dual-node, 4 gathers in flight) ----------------
template <int F, bool RELU, bool F32OUT>
__global__ __launch_bounds__(256) void aggB(const unsigned short* __restrict__ M,
                                            const int* __restrict__ rs,
                                            const int2* __restrict__ cw,
                                            const float* __restrict__ dinv,
                                            const float* __restrict__ bias,
                                            void* __restrict__ outp, int N) {
    constexpr int LPN = F / 8;          // lanes per node
    constexpr int GPB = 256 / LPN;      // thread-groups per block
    constexpr int NPB = GPB * 2;        // nodes per block (dual)
    int q = threadIdx.x % LPN;
    int gi = threadIdx.x / LPN;
    int nA = blockIdx.x * NPB + gi;
    int nB = nA + GPB;
    if (nA >= N) return;
    bool hasB = nB < N;

    float accA[8], accB[8];
    {
        float dA = dinv[nA];
        uint4 v = *(const uint4*)(M + (size_t)nA * F + q * 8);
        float sn = dA * dA;
        accA[0] = sn * bflo(v.x); accA[1] = sn * bfhi(v.x);
        accA[2] = sn * bflo(v.y); accA[3] = sn * bfhi(v.y);
        accA[4] = sn * bflo(v.z); accA[5] = sn * bfhi(v.z);
        accA[6] = sn * bflo(v.w); accA[7] = sn * bfhi(v.w);
    }
    if (hasB) {
        float dB = dinv[nB];
        uint4 v = *(const uint4*)(M + (size_t)nB * F + q * 8);
        float sn = dB * dB;
        accB[0] = sn * bflo(v.x); accB[1] = sn * bfhi(v.x);
        accB[2] = sn * bflo(v.y); accB[3] = sn * bfhi(v.y);
        accB[4] = sn * bflo(v.z); accB[5] = sn * bfhi(v.z);
        accB[6] = sn * bflo(v.w); accB[7] = sn * bfhi(v.w);
    } else {
#pragma unroll
        for (int j = 0; j < 8; j++) accB[j] = 0.f;
    }

    int kA = rs[nA], eA = rs[nA + 1];
    int kB = 0, eB = 0;
    if (hasB) { kB = rs[nB]; eB = rs[nB + 1]; }

    while (kA < eA || kB < eB) {
        int2 cA0 = (kA     < eA) ? cw[kA]     : make_int2(0, 0);
        int2 cA1 = (kA + 1 < eA) ? cw[kA + 1] : make_int2(0, 0);
        int2 cB0 = (kB     < eB) ? cw[kB]     : make_int2(0, 0);
        int2 cB1 = (kB + 1 < eB) ? cw[kB + 1] : make_int2(0, 0);
        uint4 vA0 = *(const uint4*)(M + (size_t)cA0.x * F + q * 8);
        uint4 vA1 = *(const uint4*)(M + (size_t)cA1.x * F + q * 8);
        uint4 vB0 = *(const uint4*)(M + (size_t)cB0.x * F + q * 8);
        uint4 vB1 = *(const uint4*)(M + (size_t)cB1.x * F + q * 8);
        fma8(accA, __int_as_float(cA0.y), vA0);
        fma8(accA, __int_as_float(cA1.y), vA1);
        fma8(accB, __int_as_float(cB0.y), vB0);
        fma8(accB, __int_as_float(cB1.y), vB1);
        kA += 2; kB += 2;
    }

#pragma unroll
    for (int j = 0; j < 8; j++) {
        float b = bias[q * 8 + j];
        accA[j] += b; accB[j] += b;
        if (RELU) { accA[j] = fmaxf(accA[j], 0.f); accB[j] = fmaxf(accB[j], 0.f); }
    }
    if (F32OUT) {
        float* out = (float*)outp;
        *(float4*)(out + (size_t)nA * F + q * 8)     = make_float4(accA[0], accA[1], accA[2], accA[3]);
        *(float4*)(out + (size_t)nA * F + q * 8 + 4) = make_float4(accA[4], accA[5], accA[6], accA[7]);
        if (hasB) {
            *(float4*)(out + (size_t)nB * F + q * 8)     = make_float4(accB[0], accB[1], accB[2], accB[3]);
            *(float4*)(out + (size_t)nB * F + q * 8 + 4) = make_float4(accB[4], accB[5], accB[6], accB[7]);
        }
    } else {
        unsigned short* out = (unsigned short*)outp;
        uint4 oA;
        oA.x = (unsigned int)f2bf(accA[0]) | ((unsigned int)f2bf(accA[1]) << 16);
        oA.y = (unsigned int)f2bf(accA[2]) | ((unsigned int)f2bf(accA[3]) << 16);
        oA.z = (unsigned int)f2bf(accA[4]) | ((unsigned int)f2bf(accA[5]) << 16);
        oA.w = (unsigned int)f2bf(accA[6]) | ((unsigned int)f2bf(accA[7]) << 16);
        *(uint4*)(out + (size_t)nA * F + q * 8) = oA;
        if (hasB) {
            uint4 oB;
            oB.x = (unsigned int)f2bf(accB[0]) | ((unsigned int)f2bf(accB[1]) << 16);
            oB.y = (unsigned int)f2bf(accB[2]) | ((unsigned int)f2bf(accB[3]) << 16);
            oB.z = (unsigned int)f2bf(accB[4]) | ((unsigned int)f2bf(accB[5]) << 16);
            oB.w = (unsigned int)f2bf(accB[6]) | ((unsigned int)f2bf(accB[7]) << 16);
            *(uint4*)(out + (size_t)nB * F + q * 8) = oB;
        }
    }
}

// ---------------- pooling ----------------
__global__ void gbound_k(const int* __restrict__ batch, int* __restrict__ gstart, int N, int G) {
    int i = blockIdx.x * 256 + threadIdx.x;
    if (i >= N) return;
    int b = batch[i];
    int prev = (i == 0) ? -1 : batch[i - 1];
    for (int g = prev + 1; g <= b; g++) gstart[g] = i;
    if (i == N - 1) for (int g = b + 1; g <= G; g++) gstart[g] = N;
}

__global__ __launch_bounds__(256) void pool2_k(const float* __restrict__ nod,
                                               const int* __restrict__ gstart,
                                               float* __restrict__ pool) {
    __shared__ float sh[4][64];
    int g = blockIdx.x / SPG, sub = blockIdx.x % SPG;
    int s = gstart[g], e = gstart[g + 1];
    int f = threadIdx.x % 64, r = threadIdx.x / 64;
    float acc = 0.f;
    for (int i = s + sub * 4 + r; i < e; i += SPG * 4)
        acc += nod[(size_t)i * 64 + f];
    sh[r][f] = acc;
    __syncthreads();
    if (threadIdx.x < 64) {
        float v = sh[0][f] + sh[1][f] + sh[2][f] + sh[3][f];
        atomicAdd(&pool[g * 64 + f], v);
    }
}

__global__ void final2_k(const float* __restrict__ pool, const int* __restrict__ gstart,
                         float* __restrict__ out) {
    int t = threadIdx.x;          // 512 = 8 graphs * 64 feats
    int g = t / 64, f = t % 64;
    int c = gstart[g + 1] - gstart[g];
    float v = pool[g * 64 + f] / (float)max(c, 1);
    out[g * 64 + f] = 1.f / (1.f + expf(-v));
}

// ---------------- launch ----------------
extern "C" void kernel_launch(void* const* d_in, const int* in_sizes, int n_in,
                              void* d_out, int out_size, void* d_ws, size_t ws_size,
                              hipStream_t stream) {
    const float* x     = (const float*)d_in[0];
    const int*   ei    = (const int*)d_in[1];
    const int*   batch = (const int*)d_in[2];
    const float* W_in  = (const float*)d_in[3];
    const float* b_in  = (const float*)d_in[4];
    const float* W_h   = (const float*)d_in[5];
    const float* b_h   = (const float*)d_in[6];
    const float* W_out = (const float*)d_in[7];
    const float* b_out = (const float*)d_in[8];

    const int N = in_sizes[2];
    const int E = in_sizes[1] / 2;
    const int L = in_sizes[5] / (INTER * INTER);
    const int G = 8;
    const int* src = ei;
    const int* dst = ei + E;

    char* ws = (char*)d_ws;
    size_t off = 0;
    auto alloc = [&](size_t bytes) -> void* {
        void* p = ws + off;
        off += (bytes + 255) & ~(size_t)255;
        return p;
    };
    int*   cnt    = (int*)alloc((size_t)N * 4);
    int*   cursor = (int*)alloc((size_t)N * 4);
    int*   rs     = (int*)alloc((size_t)(N + 1) * 4);
    int*   bsums  = (int*)alloc(4096);
    float* dinv   = (float*)alloc((size_t)N * 4);
    int2*  cw     = (int2*)alloc((size_t)E * 8);
    float* ax     = (float*)alloc((size_t)N * 2 * 4);
    unsigned short* h   = (unsigned short*)alloc((size_t)N * INTER * 2);
    unsigned short* m   = (unsigned short*)alloc((size_t)N * INTER * 2);
    float* hout  = (float*)alloc((size_t)N * OUTD * 4);
    unsigned short* Wht = (unsigned short*)alloc((size_t)L * INTER * INTER * 2);
    unsigned short* Wot = (unsigned short*)alloc((size_t)OUTD * INTER * 2);
    float* pool   = (float*)alloc(512 * 4);
    int*   gstart = (int*)alloc((G + 1) * 4);
    (void)ws_size; (void)n_in;

    hipMemsetAsync(cnt, 0, (size_t)N * 4, stream);
    hipMemsetAsync(cursor, 0, (size_t)N * 4, stream);
    hipMemsetAsync(pool, 0, 512 * 4, stream);

    // CSR build
    count_k<<<(E + 255) / 256, 256, 0, stream>>>(dst, cnt, E);
    dinv_k<<<(N + 255) / 256, 256, 0, stream>>>(cnt, dinv, N);
    int nsb = (N + SCAN_E - 1) / SCAN_E;
    scan_block<<<nsb, SCAN_T, 0, stream>>>(cnt, rs, bsums, N);
    scan_block<<<1, SCAN_T, 0, stream>>>(bsums, bsums, nullptr, nsb);
    scan_add<<<nsb, SCAN_T, 0, stream>>>(rs, bsums, N, E);
    scatter_k<<<(E + 255) / 256, 256, 0, stream>>>(src, dst, rs, cursor, dinv, cw, E);
    gbound_k<<<(N + 255) / 256, 256, 0, stream>>>(batch, gstart, N, G);

    // weight prep
    wprep_h<<<(L * INTER * INTER + 255) / 256, 256, 0, stream>>>(W_h, Wht, L);
    wprep_o<<<(OUTD * INTER + 255) / 256, 256, 0, stream>>>(W_out, Wot);

    // input layer
    agg2<<<(N + 255) / 256, 256, 0, stream>>>(x, rs, cw, dinv, ax, N);
    gemm_in<<<(N + 1) / 2, 256, 0, stream>>>(ax, W_in, b_in, h, N);

    // hidden layers
    for (int l = 0; l < L; l++) {
        gemm_mfma<INTER><<<(N + 63) / 64, 256, 0, stream>>>(h, Wht + (size_t)l * INTER * INTER, m, N);
        aggB<INTER, true, false><<<(N + 31) / 32, 256, 0, stream>>>(m, rs, cw, dinv, b_h + (size_t)l * INTER, h, N);
    }

    // output layer
    gemm_mfma<OUTD><<<(N + 63) / 64, 256, 0, stream>>>(h, Wot, m, N);
    aggB<OUTD, false, true><<<(N + 63) / 64, 256, 0, stream>>>(m, rs, cw, dinv, b_out, hout, N);

    // mean pool + sigmoid
    pool2_k<<<G * SPG, 256, 0, stream>>>(hout, gstart, pool);
    final2_k<<<1, 512, 0, stream>>>(pool, gstart, (float*)d_out);
}

// Round 6
// 603.133 us; speedup vs baseline: 2.6095x; 1.1189x over previous
//
#include <hip/hip_runtime.h>
#include <math.h>

// ---------------- constants ----------------
#define INTER 128
#define OUTD  64
#define SCAN_T 256
#define SCAN_E 1024
#define NSLOT 64     // graph-sum contention-spreading slots

using bf16x8 = __attribute__((ext_vector_type(8))) short;
using f32x4  = __attribute__((ext_vector_type(4))) float;

static __device__ __forceinline__ unsigned short f2bf(float f) {
    unsigned int u = __float_as_uint(f);
    u += 0x7fffu + ((u >> 16) & 1u);          // RTNE
    return (unsigned short)(u >> 16);
}
static __device__ __forceinline__ unsigned int pk2(float a, float b) {
    return (unsigned int)f2bf(a) | ((unsigned int)f2bf(b) << 16);
}
static __device__ __forceinline__ float bflo(unsigned int u) { return __uint_as_float(u << 16); }
static __device__ __forceinline__ float bfhi(unsigned int u) { return __uint_as_float(u & 0xffff0000u); }

static __device__ __forceinline__ void fma8(float* a, float w, uint4 v) {
    a[0] = fmaf(w, bflo(v.x), a[0]); a[1] = fmaf(w, bfhi(v.x), a[1]);
    a[2] = fmaf(w, bflo(v.y), a[2]); a[3] = fmaf(w, bfhi(v.y), a[3]);
    a[4] = fmaf(w, bflo(v.z), a[4]); a[5] = fmaf(w, bfhi(v.z), a[5]);
    a[6] = fmaf(w, bflo(v.w), a[6]); a[7] = fmaf(w, bfhi(v.w), a[7]);
}
static __device__ __forceinline__ void seed8(float* a, float sn, uint4 v) {
    a[0] = sn * bflo(v.x); a[1] = sn * bfhi(v.x);
    a[2] = sn * bflo(v.y); a[3] = sn * bfhi(v.y);
    a[4] = sn * bflo(v.z); a[5] = sn * bfhi(v.z);
    a[6] = sn * bflo(v.w); a[7] = sn * bfhi(v.w);
}

// ---------------- CSR build ----------------
__global__ void count_k(const int* __restrict__ dst, int* __restrict__ cnt, int E) {
    int e = blockIdx.x * 256 + threadIdx.x;
    if (e < E) atomicAdd(&cnt[dst[e]], 1);
}

__global__ void dinv_k(const int* __restrict__ cnt, float* __restrict__ dinv, int N) {
    int i = blockIdx.x * 256 + threadIdx.x;
    if (i < N) dinv[i] = rsqrtf((float)(cnt[i] + 1));
}

__global__ void scan_block(const int* __restrict__ in, int* __restrict__ out,
                           int* __restrict__ bsums, int n) {
    __shared__ int sh[SCAN_T];
    int base = blockIdx.x * SCAN_E;
    int t = threadIdx.x;
    int v[4];
    int s = 0;
#pragma unroll
    for (int i = 0; i < 4; i++) {
        int idx = base + t * 4 + i;
        v[i] = (idx < n) ? in[idx] : 0;
        s += v[i];
    }
    sh[t] = s;
    __syncthreads();
    for (int off = 1; off < SCAN_T; off <<= 1) {
        int x = (t >= off) ? sh[t - off] : 0;
        __syncthreads();
        sh[t] += x;
        __syncthreads();
    }
    int excl = (t == 0) ? 0 : sh[t - 1];
    if (bsums && t == SCAN_T - 1) bsums[blockIdx.x] = sh[t];
#pragma unroll
    for (int i = 0; i < 4; i++) {
        int idx = base + t * 4 + i;
        if (idx < n) out[idx] = excl;
        excl += v[i];
    }
}

__global__ void scan_add(int* __restrict__ out, const int* __restrict__ bsums, int n, int total) {
    int idx = blockIdx.x * SCAN_E + threadIdx.x * 4;
    int add = bsums[blockIdx.x];
#pragma unroll
    for (int i = 0; i < 4; i++) {
        int j = idx + i;
        if (j < n) out[j] += add;
    }
    if (blockIdx.x == 0 && threadIdx.x == 0) out[n] = total;
}

__global__ void scatter_k(const int* __restrict__ src, const int* __restrict__ dst,
                          const int* __restrict__ rs, int* __restrict__ cursor,
                          const float* __restrict__ dinv,
                          int2* __restrict__ cw, int E) {
    int e = blockIdx.x * 256 + threadIdx.x;
    if (e >= E) return;
    int s = src[e], d = dst[e];
    int pos = rs[d] + atomicAdd(&cursor[d], 1);
    cw[pos] = make_int2(s, __float_as_int(dinv[s] * dinv[d]));
}

// ---------------- weight prep (fp32 -> bf16, transposed [n][k]) ----------------
__global__ void wprep_h(const float* __restrict__ W, unsigned short* __restrict__ Wt, int L) {
    int tid = blockIdx.x * 256 + threadIdx.x;
    if (tid >= L * INTER * INTER) return;
    int l = tid / (INTER * INTER);
    int r = tid % (INTER * INTER);
    int n = r / INTER, k = r % INTER;
    Wt[tid] = f2bf(W[(size_t)l * INTER * INTER + (size_t)k * INTER + n]);
}

// ---------------- input layer ----------------
__global__ void agg2(const float* __restrict__ x, const int* __restrict__ rs,
                     const int2* __restrict__ cw, const float* __restrict__ dinv,
                     float* __restrict__ ax, int N) {
    int i = blockIdx.x * 256 + threadIdx.x;
    if (i >= N) return;
    float di = dinv[i];
    float sn = di * di;
    float2 xv = ((const float2*)x)[i];
    float a0 = sn * xv.x, a1 = sn * xv.y;
    int e0 = rs[i], e1 = rs[i + 1];
    for (int k = e0; k < e1; k++) {
        int2 c = cw[k];
        float wk = __int_as_float(c.y);
        float2 xs = ((const float2*)x)[c.x];
        a0 += wk * xs.x;
        a1 += wk * xs.y;
    }
    ((float2*)ax)[i] = make_float2(a0, a1);
}

// h = ax (N x 2) @ W_in (2 x 128) + b_in  -> bf16
__global__ void gemm_in(const float* __restrict__ ax, const float* __restrict__ Wi,
                        const float* __restrict__ bi, unsigned short* __restrict__ h, int N) {
    int node = blockIdx.x * 2 + threadIdx.x / 128;
    int j = threadIdx.x % 128;
    if (node >= N) return;
    float2 a = ((const float2*)ax)[node];
    h[(size_t)node * 128 + j] = f2bf(fmaf(a.x, Wi[j], fmaf(a.y, Wi[128 + j], bi[j])));
}

// ---------------- fused hidden layer: Hout = relu((A_hat Hin) W + b) ----------------
// Phase 1: dual-node CSR gather (A_hat Hin) -> bf16 LDS tile T[32][136] (padded).
// Phase 2: MFMA T @ W with swapped operands:
//   mfma(A=Wt-frag, B=T-frag): D[row=outcol][col=node]; lane (r15,kg) owns
//   node = nc*16 + r15 and 4 consecutive outcols kg*4+j per 16-col chunk.
__global__ __launch_bounds__(256) void fused_hidden(
    const unsigned short* __restrict__ Hin,
    const int* __restrict__ rs, const int2* __restrict__ cw,
    const float* __restrict__ dinv,
    const unsigned short* __restrict__ Wt,   // [128][128] bf16, Wt[n][k] = W[k][n]
    const float* __restrict__ bias,
    unsigned short* __restrict__ Hout, int N)
{
    __shared__ __align__(16) unsigned short T[32][136];
    const int t = threadIdx.x;
    const int q = t & 15;        // 16 lanes per node, lane q owns feats q*8..q*8+7
    const int gi = t >> 4;       // 0..15
    const int nA = blockIdx.x * 32 + gi;
    const int nB = nA + 16;
    const bool vA = nA < N, vB = nB < N;

    float accA[8] = {0,0,0,0,0,0,0,0}, accB[8] = {0,0,0,0,0,0,0,0};
    if (vA) {
        float dA = dinv[nA];
        seed8(accA, dA * dA, *(const uint4*)(Hin + (size_t)nA * 128 + q * 8));
    }
    if (vB) {
        float dB = dinv[nB];
        seed8(accB, dB * dB, *(const uint4*)(Hin + (size_t)nB * 128 + q * 8));
    }
    int kA = 0, eA = 0, kB = 0, eB = 0;
    if (vA) { kA = rs[nA]; eA = rs[nA + 1]; }
    if (vB) { kB = rs[nB]; eB = rs[nB + 1]; }

    while (kA < eA || kB < eB) {
        int2 cA0 = (kA     < eA) ? cw[kA]     : make_int2(0, 0);
        int2 cA1 = (kA + 1 < eA) ? cw[kA + 1] : make_int2(0, 0);
        int2 cB0 = (kB     < eB) ? cw[kB]     : make_int2(0, 0);
        int2 cB1 = (kB + 1 < eB) ? cw[kB + 1] : make_int2(0, 0);
        uint4 vA0 = *(const uint4*)(Hin + (size_t)cA0.x * 128 + q * 8);
        uint4 vA1 = *(const uint4*)(Hin + (size_t)cA1.x * 128 + q * 8);
        uint4 vB0 = *(const uint4*)(Hin + (size_t)cB0.x * 128 + q * 8);
        uint4 vB1 = *(const uint4*)(Hin + (size_t)cB1.x * 128 + q * 8);
        fma8(accA, __int_as_float(cA0.y), vA0);
        fma8(accA, __int_as_float(cA1.y), vA1);
        fma8(accB, __int_as_float(cB0.y), vB0);
        fma8(accB, __int_as_float(cB1.y), vB1);
        kA += 2; kB += 2;
    }

    // stash aggregated rows (bf16) in LDS
    {
        uint4 oA = make_uint4(pk2(accA[0], accA[1]), pk2(accA[2], accA[3]),
                              pk2(accA[4], accA[5]), pk2(accA[6], accA[7]));
        uint4 oB = make_uint4(pk2(accB[0], accB[1]), pk2(accB[2], accB[3]),
                              pk2(accB[4], accB[5]), pk2(accB[6], accB[7]));
        *(uint4*)&T[gi][q * 8] = oA;
        *(uint4*)&T[gi + 16][q * 8] = oB;
    }
    __syncthreads();

    // phase 2: 4 waves; wave = (node-chunk nc, col-half ch)
    const int wv = t >> 6;
    const int lane = t & 63;
    const int r15 = lane & 15;
    const int kg = lane >> 4;
    const int nc = wv & 1;
    const int ch = wv >> 1;

    bf16x8 bfr[4];
#pragma unroll
    for (int ks = 0; ks < 4; ks++)
        bfr[ks] = *(const bf16x8*)&T[nc * 16 + r15][kg * 8 + ks * 32];

    f32x4 acc[4];
#pragma unroll
    for (int c = 0; c < 4; c++) acc[c] = (f32x4){0.f, 0.f, 0.f, 0.f};

#pragma unroll
    for (int c = 0; c < 4; c++) {
        const unsigned short* wrow = Wt + (size_t)(ch * 64 + c * 16 + r15) * 128 + kg * 8;
#pragma unroll
        for (int ks = 0; ks < 4; ks++) {
            bf16x8 afr = *(const bf16x8*)(wrow + ks * 32);
            acc[c] = __builtin_amdgcn_mfma_f32_16x16x32_bf16(afr, bfr[ks], acc[c], 0, 0, 0);
        }
    }

    const int node = blockIdx.x * 32 + nc * 16 + r15;
    if (node < N) {
#pragma unroll
        for (int c = 0; c < 4; c++) {
            int col = ch * 64 + c * 16 + kg * 4;
            float4 bv = *(const float4*)(bias + col);
            float v0 = fmaxf(acc[c][0] + bv.x, 0.f);
            float v1 = fmaxf(acc[c][1] + bv.y, 0.f);
            float v2 = fmaxf(acc[c][2] + bv.z, 0.f);
            float v3 = fmaxf(acc[c][3] + bv.w, 0.f);
            *(uint2*)(Hout + (size_t)node * 128 + col) = make_uint2(pk2(v0, v1), pk2(v2, v3));
        }
    }
}

// ---------------- fused last layer: per-graph sums of (A_hat Hin) ----------------
__global__ __launch_bounds__(256) void fused_last(
    const unsigned short* __restrict__ Hin,
    const int* __restrict__ rs, const int2* __restrict__ cw,
    const float* __restrict__ dinv, const int* __restrict__ batch,
    float* __restrict__ gsum /* [NSLOT][8][128] */, int N)
{
    __shared__ __align__(16) float R[32][132];
    __shared__ int gid[32];
    const int t = threadIdx.x;
    const int q = t & 15;
    const int gi = t >> 4;
    const int nA = blockIdx.x * 32 + gi;
    const int nB = nA + 16;
    const bool vA = nA < N, vB = nB < N;

    float accA[8] = {0,0,0,0,0,0,0,0}, accB[8] = {0,0,0,0,0,0,0,0};
    if (vA) {
        float dA = dinv[nA];
        seed8(accA, dA * dA, *(const uint4*)(Hin + (size_t)nA * 128 + q * 8));
    }
    if (vB) {
        float dB = dinv[nB];
        seed8(accB, dB * dB, *(const uint4*)(Hin + (size_t)nB * 128 + q * 8));
    }
    int kA = 0, eA = 0, kB = 0, eB = 0;
    if (vA) { kA = rs[nA]; eA = rs[nA + 1]; }
    if (vB) { kB = rs[nB]; eB = rs[nB + 1]; }

    while (kA < eA || kB < eB) {
        int2 cA0 = (kA     < eA) ? cw[kA]     : make_int2(0, 0);
        int2 cA1 = (kA + 1 < eA) ? cw[kA + 1] : make_int2(0, 0);
        int2 cB0 = (kB     < eB) ? cw[kB]     : make_int2(0, 0);
        int2 cB1 = (kB + 1 < eB) ? cw[kB + 1] : make_int2(0, 0);
        uint4 vA0 = *(const uint4*)(Hin + (size_t)cA0.x * 128 + q * 8);
        uint4 vA1 = *(const uint4*)(Hin + (size_t)cA1.x * 128 + q * 8);
        uint4 vB0 = *(const uint4*)(Hin + (size_t)cB0.x * 128 + q * 8);
        uint4 vB1 = *(const uint4*)(Hin + (size_t)cB1.x * 128 + q * 8);
        fma8(accA, __int_as_float(cA0.y), vA0);
        fma8(accA, __int_as_float(cA1.y), vA1);
        fma8(accB, __int_as_float(cB0.y), vB0);
        fma8(accB, __int_as_float(cB1.y), vB1);
        kA += 2; kB += 2;
    }

#pragma unroll
    for (int j = 0; j < 8; j += 4) {
        *(float4*)&R[gi][q * 8 + j]      = make_float4(accA[j], accA[j+1], accA[j+2], accA[j+3]);
        *(float4*)&R[gi + 16][q * 8 + j] = make_float4(accB[j], accB[j+1], accB[j+2], accB[j+3]);
    }
    if (q == 0) {
        gid[gi]      = vA ? batch[nA] : -1;
        gid[gi + 16] = vB ? batch[nB] : -1;
    }
    __syncthreads();

    // phase 2: segment-sum 16 rows per thread-half, one atomic per (segment, feat)
    const int f = t & 127;
    const int half = t >> 7;
    const int slot = blockIdx.x & (NSLOT - 1);
    float acc = 0.f;
    int cur = -1;
    for (int r = 0; r < 16; r++) {
        int row = half * 16 + r;
        int g = gid[row];
        if (g != cur) {
            if (cur >= 0) atomicAdd(&gsum[(size_t)(slot * 8 + cur) * 128 + f], acc);
            acc = 0.f; cur = g;
        }
        if (g >= 0) acc += R[row][f];
    }
    if (cur >= 0) atomicAdd(&gsum[(size_t)(slot * 8 + cur) * 128 + f], acc);
}

// ---------------- graph boundaries + final matmul/sigmoid ----------------
__global__ void gbound_k(const int* __restrict__ batch, int* __restrict__ gstart, int N, int G) {
    int i = blockIdx.x * 256 + threadIdx.x;
    if (i >= N) return;
    int b = batch[i];
    int prev = (i == 0) ? -1 : batch[i - 1];
    for (int g = prev + 1; g <= b; g++) gstart[g] = i;
    if (i == N - 1) for (int g = b + 1; g <= G; g++) gstart[g] = N;
}

__global__ void final3_k(const float* __restrict__ gsum, const int* __restrict__ gstart,
                         const float* __restrict__ W_out, const float* __restrict__ b_out,
                         float* __restrict__ out) {
    __shared__ float sg[8][128];
    int t = threadIdx.x;  // 512
    for (int i = t; i < 1024; i += 512) {
        int g = i >> 7, f = i & 127;
        float s = 0.f;
        for (int sl = 0; sl < NSLOT; sl++) s += gsum[(size_t)(sl * 8 + g) * 128 + f];
        sg[g][f] = s;
    }
    __syncthreads();
    int g = t / 64, f = t % 64;
    float dot = 0.f;
    for (int k = 0; k < 128; k++) dot = fmaf(sg[g][k], W_out[k * 64 + f], dot);
    int c = gstart[g + 1] - gstart[g];
    float v = (c > 0) ? (dot / (float)c + b_out[f]) : 0.f;
    out[g * 64 + f] = 1.f / (1.f + expf(-v));
}

// ---------------- launch ----------------
extern "C" void kernel_launch(void* const* d_in, const int* in_sizes, int n_in,
                              void* d_out, int out_size, void* d_ws, size_t ws_size,
                              hipStream_t stream) {
    const float* x     = (const float*)d_in[0];
    const int*   ei    = (const int*)d_in[1];
    const int*   batch = (const int*)d_in[2];
    const float* W_in  = (const float*)d_in[3];
    const float* b_in  = (const float*)d_in[4];
    const float* W_h   = (const float*)d_in[5];
    const float* b_h   = (const float*)d_in[6];
    const float* W_out = (const float*)d_in[7];
    const float* b_out = (const float*)d_in[8];

    const int N = in_sizes[2];
    const int E = in_sizes[1] / 2;
    const int L = in_sizes[5] / (INTER * INTER);
    const int G = 8;
    const int* src = ei;
    const int* dst = ei + E;

    char* ws = (char*)d_ws;
    size_t off = 0;
    auto alloc = [&](size_t bytes) -> void* {
        void* p = ws + off;
        off += (bytes + 255) & ~(size_t)255;
        return p;
    };
    int*   cnt    = (int*)alloc((size_t)N * 4);
    int*   cursor = (int*)alloc((size_t)N * 4);
    int*   rs     = (int*)alloc((size_t)(N + 1) * 4);
    int*   bsums  = (int*)alloc(4096);
    float* dinv   = (float*)alloc((size_t)N * 4);
    int2*  cw     = (int2*)alloc((size_t)E * 8);
    float* ax     = (float*)alloc((size_t)N * 2 * 4);
    unsigned short* h   = (unsigned short*)alloc((size_t)N * INTER * 2);
    unsigned short* h2  = (unsigned short*)alloc((size_t)N * INTER * 2);
    unsigned short* Wht = (unsigned short*)alloc((size_t)L * INTER * INTER * 2);
    float* gsum   = (float*)alloc((size_t)NSLOT * 8 * 128 * 4);
    int*   gstart = (int*)alloc((G + 1) * 4);
    (void)ws_size; (void)n_in;

    hipMemsetAsync(cnt, 0, (size_t)N * 4, stream);
    hipMemsetAsync(cursor, 0, (size_t)N * 4, stream);
    hipMemsetAsync(gsum, 0, (size_t)NSLOT * 8 * 128 * 4, stream);

    // CSR build
    count_k<<<(E + 255) / 256, 256, 0, stream>>>(dst, cnt, E);
    dinv_k<<<(N + 255) / 256, 256, 0, stream>>>(cnt, dinv, N);
    int nsb = (N + SCAN_E - 1) / SCAN_E;
    scan_block<<<nsb, SCAN_T, 0, stream>>>(cnt, rs, bsums, N);
    scan_block<<<1, SCAN_T, 0, stream>>>(bsums, bsums, nullptr, nsb);
    scan_add<<<nsb, SCAN_T, 0, stream>>>(rs, bsums, N, E);
    scatter_k<<<(E + 255) / 256, 256, 0, stream>>>(src, dst, rs, cursor, dinv, cw, E);
    gbound_k<<<(N + 255) / 256, 256, 0, stream>>>(batch, gstart, N, G);

    // weight prep
    wprep_h<<<(L * INTER * INTER + 255) / 256, 256, 0, stream>>>(W_h, Wht, L);

    // input layer
    agg2<<<(N + 255) / 256, 256, 0, stream>>>(x, rs, cw, dinv, ax, N);
    gemm_in<<<(N + 1) / 2, 256, 0, stream>>>(ax, W_in, b_in, h, N);

    // hidden layers (fused gather + MFMA transform), ping-pong h <-> h2
    unsigned short* hin = h;
    unsigned short* hout = h2;
    for (int l = 0; l < L; l++) {
        fused_hidden<<<(N + 31) / 32, 256, 0, stream>>>(
            hin, rs, cw, dinv, Wht + (size_t)l * INTER * INTER, b_h + (size_t)l * INTER, hout, N);
        unsigned short* tmp = hin; hin = hout; hout = tmp;
    }

    // output layer: gather + per-graph reduce, then tiny fp32 matmul + sigmoid
    fused_last<<<(N + 31) / 32, 256, 0, stream>>>(hin, rs, cw, dinv, batch, gsum, N);
    final3_k<<<1, 512, 0, stream>>>(gsum, gstart, W_out, b_out, (float*)d_out);
}

// Round 7
// 564.169 us; speedup vs baseline: 2.7898x; 1.0691x over previous
//
#include <hip/hip_runtime.h>
#include <math.h>

// ---------------- constants ----------------
#define INTER 128
#define OUTD  64
#define SCAN_T 256
#define SCAN_E 1024
#define NSLOT 64     // graph-sum contention-spreading slots

using bf16x8 = __attribute__((ext_vector_type(8))) short;
using f32x4  = __attribute__((ext_vector_type(4))) float;

static __device__ __forceinline__ unsigned short f2bf(float f) {
    unsigned int u = __float_as_uint(f);
    u += 0x7fffu + ((u >> 16) & 1u);          // RTNE
    return (unsigned short)(u >> 16);
}
static __device__ __forceinline__ unsigned int pk2(float a, float b) {
    return (unsigned int)f2bf(a) | ((unsigned int)f2bf(b) << 16);
}
static __device__ __forceinline__ float bflo(unsigned int u) { return __uint_as_float(u << 16); }
static __device__ __forceinline__ float bfhi(unsigned int u) { return __uint_as_float(u & 0xffff0000u); }

static __device__ __forceinline__ void fma8(float* a, float w, uint4 v) {
    a[0] = fmaf(w, bflo(v.x), a[0]); a[1] = fmaf(w, bfhi(v.x), a[1]);
    a[2] = fmaf(w, bflo(v.y), a[2]); a[3] = fmaf(w, bfhi(v.y), a[3]);
    a[4] = fmaf(w, bflo(v.z), a[4]); a[5] = fmaf(w, bfhi(v.z), a[5]);
    a[6] = fmaf(w, bflo(v.w), a[6]); a[7] = fmaf(w, bfhi(v.w), a[7]);
}
static __device__ __forceinline__ void seed8(float* a, float sn, uint4 v) {
    a[0] = sn * bflo(v.x); a[1] = sn * bfhi(v.x);
    a[2] = sn * bflo(v.y); a[3] = sn * bfhi(v.y);
    a[4] = sn * bflo(v.z); a[5] = sn * bfhi(v.z);
    a[6] = sn * bflo(v.w); a[7] = sn * bfhi(v.w);
}
static __device__ __forceinline__ void seed4(float* a, float sn, uint2 v) {
    a[0] = sn * bflo(v.x); a[1] = sn * bfhi(v.x);
    a[2] = sn * bflo(v.y); a[3] = sn * bfhi(v.y);
}

// ---------------- CSR build ----------------
__global__ void count_k(const int* __restrict__ dst, int* __restrict__ cnt, int E) {
    int e = blockIdx.x * 256 + threadIdx.x;
    if (e < E) atomicAdd(&cnt[dst[e]], 1);
}

__global__ void dinv_k(const int* __restrict__ cnt, float* __restrict__ dinv, int N) {
    int i = blockIdx.x * 256 + threadIdx.x;
    if (i < N) dinv[i] = rsqrtf((float)(cnt[i] + 1));
}

__global__ void scan_block(const int* __restrict__ in, int* __restrict__ out,
                           int* __restrict__ bsums, int n) {
    __shared__ int sh[SCAN_T];
    int base = blockIdx.x * SCAN_E;
    int t = threadIdx.x;
    int v[4];
    int s = 0;
#pragma unroll
    for (int i = 0; i < 4; i++) {
        int idx = base + t * 4 + i;
        v[i] = (idx < n) ? in[idx] : 0;
        s += v[i];
    }
    sh[t] = s;
    __syncthreads();
    for (int off = 1; off < SCAN_T; off <<= 1) {
        int x = (t >= off) ? sh[t - off] : 0;
        __syncthreads();
        sh[t] += x;
        __syncthreads();
    }
    int excl = (t == 0) ? 0 : sh[t - 1];
    if (bsums && t == SCAN_T - 1) bsums[blockIdx.x] = sh[t];
#pragma unroll
    for (int i = 0; i < 4; i++) {
        int idx = base + t * 4 + i;
        if (idx < n) out[idx] = excl;
        excl += v[i];
    }
}

__global__ void scan_add(int* __restrict__ out, const int* __restrict__ bsums, int n, int total) {
    int idx = blockIdx.x * SCAN_E + threadIdx.x * 4;
    int add = bsums[blockIdx.x];
#pragma unroll
    for (int i = 0; i < 4; i++) {
        int j = idx + i;
        if (j < n) out[j] += add;
    }
    if (blockIdx.x == 0 && threadIdx.x == 0) out[n] = total;
}

__global__ void scatter_k(const int* __restrict__ src, const int* __restrict__ dst,
                          const int* __restrict__ rs, int* __restrict__ cursor,
                          const float* __restrict__ dinv,
                          int2* __restrict__ cw, int E) {
    int e = blockIdx.x * 256 + threadIdx.x;
    if (e >= E) return;
    int s = src[e], d = dst[e];
    int pos = rs[d] + atomicAdd(&cursor[d], 1);
    cw[pos] = make_int2(s, __float_as_int(dinv[s] * dinv[d]));
}

// ---------------- weight prep (fp32 -> bf16, transposed [n][k]) ----------------
__global__ void wprep_h(const float* __restrict__ W, unsigned short* __restrict__ Wt, int L) {
    int tid = blockIdx.x * 256 + threadIdx.x;
    if (tid >= L * INTER * INTER) return;
    int l = tid / (INTER * INTER);
    int r = tid % (INTER * INTER);
    int n = r / INTER, k = r % INTER;
    Wt[tid] = f2bf(W[(size_t)l * INTER * INTER + (size_t)k * INTER + n]);
}

__global__ void wprep_o(const float* __restrict__ W, unsigned short* __restrict__ Wt) {
    int tid = blockIdx.x * 256 + threadIdx.x;
    if (tid >= OUTD * INTER) return;
    int n = tid / INTER, k = tid % INTER;
    Wt[tid] = f2bf(W[(size_t)k * OUTD + n]);
}

// ---------------- input layer ----------------
__global__ void agg2(const float* __restrict__ x, const int* __restrict__ rs,
                     const int2* __restrict__ cw, const float* __restrict__ dinv,
                     float* __restrict__ ax, int N) {
    int i = blockIdx.x * 256 + threadIdx.x;
    if (i >= N) return;
    float di = dinv[i];
    float sn = di * di;
    float2 xv = ((const float2*)x)[i];
    float a0 = sn * xv.x, a1 = sn * xv.y;
    int e0 = rs[i], e1 = rs[i + 1];
    for (int k = e0; k < e1; k++) {
        int2 c = cw[k];
        float wk = __int_as_float(c.y);
        float2 xs = ((const float2*)x)[c.x];
        a0 += wk * xs.x;
        a1 += wk * xs.y;
    }
    ((float2*)ax)[i] = make_float2(a0, a1);
}

// h = ax (N x 2) @ W_in (2 x 128) + b_in  -> bf16
__global__ void gemm_in(const float* __restrict__ ax, const float* __restrict__ Wi,
                        const float* __restrict__ bi, unsigned short* __restrict__ h, int N) {
    int node = blockIdx.x * 2 + threadIdx.x / 128;
    int j = threadIdx.x % 128;
    if (node >= N) return;
    float2 a = ((const float2*)ax)[node];
    h[(size_t)node * 128 + j] = f2bf(fmaf(a.x, Wi[j], fmaf(a.y, Wi[128 + j], bi[j])));
}

// ---------------- fused hidden layer: Hout = relu((A_hat Hin) W + b) ----------------
// Phase 1: dual-node, quad-edge CSR gather (8 loads in flight) -> bf16 LDS T[32][136].
// Phase 2: wave w owns cols [w*32,(w+1)*32) x BOTH node chunks; each W-frag is
//          loaded once and feeds 2 MFMAs -> Wt read exactly once per block.
__global__ __launch_bounds__(256) void fused_hidden2(
    const unsigned short* __restrict__ Hin,
    const int* __restrict__ rs, const int2* __restrict__ cw,
    const float* __restrict__ dinv,
    const unsigned short* __restrict__ Wt,   // [128][128] bf16, Wt[n][k] = W[k][n]
    const float* __restrict__ bias,
    unsigned short* __restrict__ Hout, int N)
{
    __shared__ __align__(16) unsigned short T[32][136];
    const int t = threadIdx.x;
    const int q = t & 15;        // 16 lanes per node
    const int gi = t >> 4;       // 0..15
    const int nA = blockIdx.x * 32 + gi;
    const int nB = nA + 16;
    const bool vA = nA < N, vB = nB < N;

    float accA[8] = {0,0,0,0,0,0,0,0}, accB[8] = {0,0,0,0,0,0,0,0};
    if (vA) {
        float dA = dinv[nA];
        seed8(accA, dA * dA, *(const uint4*)(Hin + (size_t)nA * 128 + q * 8));
    }
    if (vB) {
        float dB = dinv[nB];
        seed8(accB, dB * dB, *(const uint4*)(Hin + (size_t)nB * 128 + q * 8));
    }
    int kA = 0, eA = 0, kB = 0, eB = 0;
    if (vA) { kA = rs[nA]; eA = rs[nA + 1]; }
    if (vB) { kB = rs[nB]; eB = rs[nB + 1]; }

    while (kA < eA || kB < eB) {
        int2 cA0 = (kA     < eA) ? cw[kA]     : make_int2(0, 0);
        int2 cA1 = (kA + 1 < eA) ? cw[kA + 1] : make_int2(0, 0);
        int2 cA2 = (kA + 2 < eA) ? cw[kA + 2] : make_int2(0, 0);
        int2 cA3 = (kA + 3 < eA) ? cw[kA + 3] : make_int2(0, 0);
        int2 cB0 = (kB     < eB) ? cw[kB]     : make_int2(0, 0);
        int2 cB1 = (kB + 1 < eB) ? cw[kB + 1] : make_int2(0, 0);
        int2 cB2 = (kB + 2 < eB) ? cw[kB + 2] : make_int2(0, 0);
        int2 cB3 = (kB + 3 < eB) ? cw[kB + 3] : make_int2(0, 0);
        uint4 vA0 = *(const uint4*)(Hin + (size_t)cA0.x * 128 + q * 8);
        uint4 vA1 = *(const uint4*)(Hin + (size_t)cA1.x * 128 + q * 8);
        uint4 vA2 = *(const uint4*)(Hin + (size_t)cA2.x * 128 + q * 8);
        uint4 vA3 = *(const uint4*)(Hin + (size_t)cA3.x * 128 + q * 8);
        uint4 vB0 = *(const uint4*)(Hin + (size_t)cB0.x * 128 + q * 8);
        uint4 vB1 = *(const uint4*)(Hin + (size_t)cB1.x * 128 + q * 8);
        uint4 vB2 = *(const uint4*)(Hin + (size_t)cB2.x * 128 + q * 8);
        uint4 vB3 = *(const uint4*)(Hin + (size_t)cB3.x * 128 + q * 8);
        fma8(accA, __int_as_float(cA0.y), vA0);
        fma8(accA, __int_as_float(cA1.y), vA1);
        fma8(accA, __int_as_float(cA2.y), vA2);
        fma8(accA, __int_as_float(cA3.y), vA3);
        fma8(accB, __int_as_float(cB0.y), vB0);
        fma8(accB, __int_as_float(cB1.y), vB1);
        fma8(accB, __int_as_float(cB2.y), vB2);
        fma8(accB, __int_as_float(cB3.y), vB3);
        kA += 4; kB += 4;
    }

    {
        uint4 oA = make_uint4(pk2(accA[0], accA[1]), pk2(accA[2], accA[3]),
                              pk2(accA[4], accA[5]), pk2(accA[6], accA[7]));
        uint4 oB = make_uint4(pk2(accB[0], accB[1]), pk2(accB[2], accB[3]),
                              pk2(accB[4], accB[5]), pk2(accB[6], accB[7]));
        *(uint4*)&T[gi][q * 8] = oA;
        *(uint4*)&T[gi + 16][q * 8] = oB;
    }
    __syncthreads();

    // phase 2
    const int wv = t >> 6;       // wave -> col slice [wv*32, wv*32+32)
    const int lane = t & 63;
    const int r15 = lane & 15;
    const int kg = lane >> 4;

    bf16x8 bfr[2][4];
#pragma unroll
    for (int nc = 0; nc < 2; nc++)
#pragma unroll
        for (int ks = 0; ks < 4; ks++)
            bfr[nc][ks] = *(const bf16x8*)&T[nc * 16 + r15][kg * 8 + ks * 32];

    f32x4 acc[2][2];
#pragma unroll
    for (int nc = 0; nc < 2; nc++)
#pragma unroll
        for (int c = 0; c < 2; c++) acc[nc][c] = (f32x4){0.f, 0.f, 0.f, 0.f};

#pragma unroll
    for (int c = 0; c < 2; c++) {
        const unsigned short* wrow = Wt + (size_t)(wv * 32 + c * 16 + r15) * 128 + kg * 8;
#pragma unroll
        for (int ks = 0; ks < 4; ks++) {
            bf16x8 afr = *(const bf16x8*)(wrow + ks * 32);
            acc[0][c] = __builtin_amdgcn_mfma_f32_16x16x32_bf16(afr, bfr[0][ks], acc[0][c], 0, 0, 0);
            acc[1][c] = __builtin_amdgcn_mfma_f32_16x16x32_bf16(afr, bfr[1][ks], acc[1][c], 0, 0, 0);
        }
    }

#pragma unroll
    for (int nc = 0; nc < 2; nc++) {
        const int node = blockIdx.x * 32 + nc * 16 + r15;
        if (node < N) {
#pragma unroll
            for (int c = 0; c < 2; c++) {
                int col = wv * 32 + c * 16 + kg * 4;
                float4 bv = *(const float4*)(bias + col);
                float v0 = fmaxf(acc[nc][c][0] + bv.x, 0.f);
                float v1 = fmaxf(acc[nc][c][1] + bv.y, 0.f);
                float v2 = fmaxf(acc[nc][c][2] + bv.z, 0.f);
                float v3 = fmaxf(acc[nc][c][3] + bv.w, 0.f);
                *(uint2*)(Hout + (size_t)node * 128 + col) = make_uint2(pk2(v0, v1), pk2(v2, v3));
            }
        }
    }
}

// ---------------- output transform: g = Hin (N x 128) @ W_out (128 x 64) -> bf16 ----------------
__global__ __launch_bounds__(256) void gemm_out(const unsigned short* __restrict__ Hin,
                                                const unsigned short* __restrict__ Wt, // [64][128]
                                                unsigned short* __restrict__ g, int N) {
    const int wv = threadIdx.x >> 6;
    const int lane = threadIdx.x & 63;
    const int r15 = lane & 15;
    const int kg = lane >> 4;
    const int node0 = blockIdx.x * 64 + wv * 16;
    if (node0 >= N) return;

    int arow = node0 + r15;
    if (arow >= N) arow = N - 1;
    bf16x8 bfr[4];
#pragma unroll
    for (int ks = 0; ks < 4; ks++)
        bfr[ks] = *(const bf16x8*)(Hin + (size_t)arow * 128 + kg * 8 + ks * 32);

    f32x4 acc[4];
#pragma unroll
    for (int c = 0; c < 4; c++) acc[c] = (f32x4){0.f, 0.f, 0.f, 0.f};

#pragma unroll
    for (int c = 0; c < 4; c++) {
        const unsigned short* wrow = Wt + (size_t)(c * 16 + r15) * 128 + kg * 8;
#pragma unroll
        for (int ks = 0; ks < 4; ks++) {
            bf16x8 afr = *(const bf16x8*)(wrow + ks * 32);
            acc[c] = __builtin_amdgcn_mfma_f32_16x16x32_bf16(afr, bfr[ks], acc[c], 0, 0, 0);
        }
    }
    // D[row=outcol][col=node]: lane (r15,kg) holds node r15, outcols c*16+kg*4+j
    const int node = node0 + r15;
    if (node < N) {
#pragma unroll
        for (int c = 0; c < 4; c++) {
            int col = c * 16 + kg * 4;
            *(uint2*)(g + (size_t)node * 64 + col) =
                make_uint2(pk2(acc[c][0], acc[c][1]), pk2(acc[c][2], acc[c][3]));
        }
    }
}

// ---------------- fused last: gather g (64-wide) + per-graph segment sums ----------------
__global__ __launch_bounds__(256) void fused_last2(
    const unsigned short* __restrict__ g,
    const int* __restrict__ rs, const int2* __restrict__ cw,
    const float* __restrict__ dinv, const int* __restrict__ batch,
    float* __restrict__ gsum /* [NSLOT][8][64] */, int N)
{
    __shared__ __align__(16) float R[64][68];
    __shared__ int gid[64];
    const int t = threadIdx.x;
    const int q = t & 7;         // 8 lanes per node (64 feats, 8 each)
    const int gi = t >> 3;       // 0..31
    const int nA = blockIdx.x * 64 + gi;
    const int nB = nA + 32;
    const bool vA = nA < N, vB = nB < N;

    float accA[8] = {0,0,0,0,0,0,0,0}, accB[8] = {0,0,0,0,0,0,0,0};
    if (vA) {
        float dA = dinv[nA];
        seed8(accA, dA * dA, *(const uint4*)(g + (size_t)nA * 64 + q * 8));
    }
    if (vB) {
        float dB = dinv[nB];
        seed8(accB, dB * dB, *(const uint4*)(g + (size_t)nB * 64 + q * 8));
    }
    int kA = 0, eA = 0, kB = 0, eB = 0;
    if (vA) { kA = rs[nA]; eA = rs[nA + 1]; }
    if (vB) { kB = rs[nB]; eB = rs[nB + 1]; }

    while (kA < eA || kB < eB) {
        int2 cA0 = (kA     < eA) ? cw[kA]     : make_int2(0, 0);
        int2 cA1 = (kA + 1 < eA) ? cw[kA + 1] : make_int2(0, 0);
        int2 cA2 = (kA + 2 < eA) ? cw[kA + 2] : make_int2(0, 0);
        int2 cA3 = (kA + 3 < eA) ? cw[kA + 3] : make_int2(0, 0);
        int2 cB0 = (kB     < eB) ? cw[kB]     : make_int2(0, 0);
        int2 cB1 = (kB + 1 < eB) ? cw[kB + 1] : make_int2(0, 0);
        int2 cB2 = (kB + 2 < eB) ? cw[kB + 2] : make_int2(0, 0);
        int2 cB3 = (kB + 3 < eB) ? cw[kB + 3] : make_int2(0, 0);
        uint4 vA0 = *(const uint4*)(g + (size_t)cA0.x * 64 + q * 8);
        uint4 vA1 = *(const uint4*)(g + (size_t)cA1.x * 64 + q * 8);
        uint4 vA2 = *(const uint4*)(g + (size_t)cA2.x * 64 + q * 8);
        uint4 vA3 = *(const uint4*)(g + (size_t)cA3.x * 64 + q * 8);
        uint4 vB0 = *(const uint4*)(g + (size_t)cB0.x * 64 + q * 8);
        uint4 vB1 = *(const uint4*)(g + (size_t)cB1.x * 64 + q * 8);
        uint4 vB2 = *(const uint4*)(g + (size_t)cB2.x * 64 + q * 8);
        uint4 vB3 = *(const uint4*)(g + (size_t)cB3.x * 64 + q * 8);
        fma8(accA, __int_as_float(cA0.y), vA0);
        fma8(accA, __int_as_float(cA1.y), vA1);
        fma8(accA, __int_as_float(cA2.y), vA2);
        fma8(accA, __int_as_float(cA3.y), vA3);
        fma8(accB, __int_as_float(cB0.y), vB0);
        fma8(accB, __int_as_float(cB1.y), vB1);
        fma8(accB, __int_as_float(cB2.y), vB2);
        fma8(accB, __int_as_float(cB3.y), vB3);
        kA += 4; kB += 4;
    }

#pragma unroll
    for (int j = 0; j < 8; j += 4) {
        *(float4*)&R[gi][q * 8 + j]      = make_float4(accA[j], accA[j+1], accA[j+2], accA[j+3]);
        *(float4*)&R[gi + 32][q * 8 + j] = make_float4(accB[j], accB[j+1], accB[j+2], accB[j+3]);
    }
    if (q == 0) {
        gid[gi]      = vA ? batch[nA] : -1;
        gid[gi + 32] = vB ? batch[nB] : -1;
    }
    __syncthreads();

    // segment-sum: quarter h scans 16 rows for feat f
    const int f = t & 63;
    const int half = t >> 6;     // 0..3
    const int slot = blockIdx.x & (NSLOT - 1);
    float acc = 0.f;
    int cur = -1;
    for (int r = 0; r < 16; r++) {
        int row = half * 16 + r;
        int gg = gid[row];
        if (gg != cur) {
            if (cur >= 0) atomicAdd(&gsum[(size_t)(slot * 8 + cur) * 64 + f], acc);
            acc = 0.f; cur = gg;
        }
        if (gg >= 0) acc += R[row][f];
    }
    if (cur >= 0) atomicAdd(&gsum[(size_t)(slot * 8 + cur) * 64 + f], acc);
}

// ---------------- graph boundaries + final mean/bias/sigmoid ----------------
__global__ void gbound_k(const int* __restrict__ batch, int* __restrict__ gstart, int N, int G) {
    int i = blockIdx.x * 256 + threadIdx.x;
    if (i >= N) return;
    int b = batch[i];
    int prev = (i == 0) ? -1 : batch[i - 1];
    for (int g = prev + 1; g <= b; g++) gstart[g] = i;
    if (i == N - 1) for (int g = b + 1; g <= G; g++) gstart[g] = N;
}

__global__ void final4_k(const float* __restrict__ gsum, const int* __restrict__ gstart,
                         const float* __restrict__ b_out, float* __restrict__ out) {
    int t = threadIdx.x;          // 512 = 8 graphs * 64 feats
    int g = t >> 6, f = t & 63;
    float s = 0.f;
    for (int sl = 0; sl < NSLOT; sl++) s += gsum[(size_t)(sl * 8 + g) * 64 + f];
    int c = gstart[g + 1] - gstart[g];
    float v = s / (float)max(c, 1) + b_out[f];
    out[g * 64 + f] = 1.f / (1.f + expf(-v));
}

// ---------------- launch ----------------
extern "C" void kernel_launch(void* const* d_in, const int* in_sizes, int n_in,
                              void* d_out, int out_size, void* d_ws, size_t ws_size,
                              hipStream_t stream) {
    const float* x     = (const float*)d_in[0];
    const int*   ei    = (const int*)d_in[1];
    const int*   batch = (const int*)d_in[2];
    const float* W_in  = (const float*)d_in[3];
    const float* b_in  = (const float*)d_in[4];
    const float* W_h   = (const float*)d_in[5];
    const float* b_h   = (const float*)d_in[6];
    const float* W_out = (const float*)d_in[7];
    const float* b_out = (const float*)d_in[8];

    const int N = in_sizes[2];
    const int E = in_sizes[1] / 2;
    const int L = in_sizes[5] / (INTER * INTER);
    const int G = 8;
    const int* src = ei;
    const int* dst = ei + E;

    char* ws = (char*)d_ws;
    size_t off = 0;
    auto alloc = [&](size_t bytes) -> void* {
        void* p = ws + off;
        off += (bytes + 255) & ~(size_t)255;
        return p;
    };
    int*   cnt    = (int*)alloc((size_t)N * 4);
    int*   cursor = (int*)alloc((size_t)N * 4);
    int*   rs     = (int*)alloc((size_t)(N + 1) * 4);
    int*   bsums  = (int*)alloc(4096);
    float* dinv   = (float*)alloc((size_t)N * 4);
    int2*  cw     = (int2*)alloc((size_t)E * 8);
    float* ax     = (float*)alloc((size_t)N * 2 * 4);
    unsigned short* h   = (unsigned short*)alloc((size_t)N * INTER * 2);
    unsigned short* h2  = (unsigned short*)alloc((size_t)N * INTER * 2);
    unsigned short* g   = (unsigned short*)alloc((size_t)N * OUTD * 2);
    unsigned short* Wht = (unsigned short*)alloc((size_t)L * INTER * INTER * 2);
    unsigned short* Wot = (unsigned short*)alloc((size_t)OUTD * INTER * 2);
    float* gsum   = (float*)alloc((size_t)NSLOT * 8 * OUTD * 4);
    int*   gstart = (int*)alloc((G + 1) * 4);
    (void)ws_size; (void)n_in;

    hipMemsetAsync(cnt, 0, (size_t)N * 4, stream);
    hipMemsetAsync(cursor, 0, (size_t)N * 4, stream);
    hipMemsetAsync(gsum, 0, (size_t)NSLOT * 8 * OUTD * 4, stream);

    // CSR build
    count_k<<<(E + 255) / 256, 256, 0, stream>>>(dst, cnt, E);
    dinv_k<<<(N + 255) / 256, 256, 0, stream>>>(cnt, dinv, N);
    int nsb = (N + SCAN_E - 1) / SCAN_E;
    scan_block<<<nsb, SCAN_T, 0, stream>>>(cnt, rs, bsums, N);
    scan_block<<<1, SCAN_T, 0, stream>>>(bsums, bsums, nullptr, nsb);
    scan_add<<<nsb, SCAN_T, 0, stream>>>(rs, bsums, N, E);
    scatter_k<<<(E + 255) / 256, 256, 0, stream>>>(src, dst, rs, cursor, dinv, cw, E);
    gbound_k<<<(N + 255) / 256, 256, 0, stream>>>(batch, gstart, N, G);

    // weight prep
    wprep_h<<<(L * INTER * INTER + 255) / 256, 256, 0, stream>>>(W_h, Wht, L);
    wprep_o<<<(OUTD * INTER + 255) / 256, 256, 0, stream>>>(W_out, Wot);

    // input layer
    agg2<<<(N + 255) / 256, 256, 0, stream>>>(x, rs, cw, dinv, ax, N);
    gemm_in<<<(N + 1) / 2, 256, 0, stream>>>(ax, W_in, b_in, h, N);

    // hidden layers (fused gather + MFMA transform), ping-pong h <-> h2
    unsigned short* hin = h;
    unsigned short* hout = h2;
    for (int l = 0; l < L; l++) {
        fused_hidden2<<<(N + 31) / 32, 256, 0, stream>>>(
            hin, rs, cw, dinv, Wht + (size_t)l * INTER * INTER, b_h + (size_t)l * INTER, hout, N);
        unsigned short* tmp = hin; hin = hout; hout = tmp;
    }

    // output layer: transform-first (halves gather width), then gather + pool
    gemm_out<<<(N + 63) / 64, 256, 0, stream>>>(hin, Wot, g, N);
    fused_last2<<<(N + 63) / 64, 256, 0, stream>>>(g, rs, cw, dinv, batch, gsum, N);
    final4_k<<<1, 512, 0, stream>>>(gsum, gstart, b_out, (float*)d_out);
}